// Round 1
// 3654.247 us; speedup vs baseline: 1.2664x; 1.2664x over previous
//
#include <hip/hip_runtime.h>

// Problem constants
#define T_STEPS 128
#define BATCH   64
#define VOCAB   8192
#define HID     2048
#define WROW    (VOCAB + HID)   // 10240, hidden_w row length
#define BH      (BATCH * HID)   // 131072, one state slab
#define CNT_STRIDE 512          // ints per bm-group counter array (padded)

typedef __bf16 bf16_t;
typedef __bf16 bf16x8 __attribute__((ext_vector_type(8)));
typedef float  f32x4  __attribute__((ext_vector_type(4)));

// ---------------------------------------------------------------------------
// Convert W_hh = hidden_w[:, V:] (2048x2048 fp32) -> bf16, row-major [h][j].
// Block 0 additionally zeroes the step-barrier counters (stream-ordered
// before rnn_persist, so counters are reset on every kernel_launch call).
__global__ void conv_whh(const float* __restrict__ hw, bf16_t* __restrict__ whh,
                         int* __restrict__ cnt) {
    if (blockIdx.x == 0) {
        for (int i = threadIdx.x; i < 4 * CNT_STRIDE; i += 256) cnt[i] = 0;
    }
    int idx = blockIdx.x * 256 + threadIdx.x;
    int i4 = idx * 4;
    int h = i4 >> 11;
    int j = i4 & 2047;
    float4 w = *(const float4*)(hw + (size_t)h * WROW + VOCAB + j);
    union { bf16_t b[4]; uint2 u; } t;
    t.b[0] = (bf16_t)w.x; t.b[1] = (bf16_t)w.y; t.b[2] = (bf16_t)w.z; t.b[3] = (bf16_t)w.w;
    *(uint2*)(whh + (size_t)h * HID + j) = t.u;
}

// Convert output_w (8192x2048 fp32, contiguous) -> bf16
__global__ void conv_wout(const float* __restrict__ wo, bf16_t* __restrict__ wob) {
    size_t i4 = ((size_t)blockIdx.x * 256 + threadIdx.x) * 4;
    float4 w = *(const float4*)(wo + i4);
    union { bf16_t b[4]; uint2 u; } t;
    t.b[0] = (bf16_t)w.x; t.b[1] = (bf16_t)w.y; t.b[2] = (bf16_t)w.z; t.b[3] = (bf16_t)w.w;
    *(uint2*)(wob + i4) = t.u;
}

// Transpose+convert embedding block: wembT[v][h] = hidden_w[h][v], bf16
// grid (V/32, H/32), block (32, 8)
__global__ void trans_emb(const float* __restrict__ hw, bf16_t* __restrict__ wt) {
    __shared__ float tile[32][33];
    int tx = threadIdx.x, ty = threadIdx.y;
    int v0 = blockIdx.x * 32, h0 = blockIdx.y * 32;
#pragma unroll
    for (int i = 0; i < 4; i++)
        tile[ty + i * 8][tx] = hw[(size_t)(h0 + ty + i * 8) * WROW + v0 + tx];
    __syncthreads();
#pragma unroll
    for (int i = 0; i < 4; i++)
        wt[(size_t)(v0 + ty + i * 8) * HID + h0 + tx] = (bf16_t)tile[tx][ty + i * 8];
}

// ---------------------------------------------------------------------------
// Persistent cooperative recurrence kernel: all 128 steps in one launch.
// Grid 256 blocks x 512 threads. Block (bm,bn): bm = m-slice of 16 batch rows,
// bn = n-slice of 32 hidden cols. 8 waves split K (2048) -> 256 each.
// Whh slice lives in registers for the whole kernel (16 bf16x8 frags/lane).
//
// Sync: batch rows are independent, so block (bm,bn) at step t only needs the
// 64 blocks sharing its bm to have written state slab t. Hand-rolled per-group
// barrier: arrive = RELEASE fetch_add (emits buffer_wbl2 -> L2 flushed to the
// L3 coherence point); wait = relaxed agent-scope poll (bypasses L2) + one
// ACQUIRE agent fence (buffer_inv) before the A-tile loads. This replaces the
// ~30 us/step cg::grid.sync() (256-block, s_sleep-backoff) with 4 independent
// 64-block barriers and no sleep-backoff. Cooperative launch is kept solely
// for the co-residency guarantee.
__launch_bounds__(512)
__global__ void rnn_persist(bf16_t* __restrict__ states,    // (T+1) slabs of 64x2048
                            const bf16_t* __restrict__ whh, // 2048 x 2048 [h][k]
                            const bf16_t* __restrict__ wembT,// 8192 x 2048 [v][h]
                            const float* __restrict__ hb,   // 2048
                            const int* __restrict__ toks,   // T*B
                            float* __restrict__ fin,        // 64 x 2048 fp32
                            int* __restrict__ cnt) {        // 4 * CNT_STRIDE ints
    __shared__ float part[8][512];                           // 16 KB

    const int tid = threadIdx.x;
    const int w = tid >> 6, lane = tid & 63;
    const int q = lane >> 4, l15 = lane & 15;
    const int bm = blockIdx.x & 3, bn = blockIdx.x >> 2;
    const int m0 = bm * 16, n0 = bn * 32;
    const int kb = w * 256;                                  // this wave's K base

    // Load persistent B fragments: B[n0+nt*16+l15][kb + kk*32 + q*8 .. +8]
    bf16x8 breg[2][8];
#pragma unroll
    for (int nt = 0; nt < 2; nt++)
#pragma unroll
        for (int kk = 0; kk < 8; kk++)
            breg[nt][kk] = *(const bf16x8*)(
                whh + (size_t)(n0 + nt * 16 + l15) * HID + kb + kk * 32 + q * 8);

    const int abase = (m0 + l15) * HID + kb + q * 8;         // lane's A offset
    const int r = tid >> 5, c = tid & 31;                    // epilogue output
    const int R = m0 + r, h = n0 + c;
    const float bias = hb[h];
    int* grpCnt = cnt + bm * CNT_STRIDE;                     // this group's counters

    for (int t = 0; t < T_STEPS; ++t) {
        // State-independent prefetch, hoisted ABOVE the barrier wait:
        // tokens and embedding weights are constants, so the acquire
        // invalidate cannot make them stale.
        const int tok = toks[t * BATCH + R];
        const float embv = (float)wembT[(size_t)tok * HID + h];

        f32x4 acc0 = (f32x4){0.f, 0.f, 0.f, 0.f};
        f32x4 acc1 = (f32x4){0.f, 0.f, 0.f, 0.f};
        if (t > 0) {
            // Wait until all 64 blocks of this bm-group published slab t.
            while (__hip_atomic_load(&grpCnt[t], __ATOMIC_RELAXED,
                                     __HIP_MEMORY_SCOPE_AGENT) < 64)
                __builtin_amdgcn_s_sleep(2);
            __builtin_amdgcn_fence(__ATOMIC_ACQUIRE, "agent");

            const bf16_t* sprev = states + (size_t)t * BH;
            bf16x8 areg[8];
#pragma unroll
            for (int kk = 0; kk < 8; kk++)
                areg[kk] = *(const bf16x8*)(sprev + abase + kk * 32);
#pragma unroll
            for (int kk = 0; kk < 8; kk++) {
                acc0 = __builtin_amdgcn_mfma_f32_16x16x32_bf16(areg[kk], breg[0][kk], acc0, 0, 0, 0);
                acc1 = __builtin_amdgcn_mfma_f32_16x16x32_bf16(areg[kk], breg[1][kk], acc1, 0, 0, 0);
            }
        }
        // write K-partials: C/D layout col = l15, row = q*4 + i
#pragma unroll
        for (int i = 0; i < 4; i++) {
            part[w][(q * 4 + i) * 32 + l15]      = acc0[i];
            part[w][(q * 4 + i) * 32 + 16 + l15] = acc1[i];
        }
        __syncthreads();
        // epilogue: one output element per thread
        {
            float s = 0.f;
#pragma unroll
            for (int ww = 0; ww < 8; ww++) s += part[ww][tid];
            float v = tanhf(s + embv + bias);
            states[(size_t)(t + 1) * BH + R * HID + h] = (bf16_t)v;
            if (t == T_STEPS - 1) fin[R * HID + h] = v;
        }
        // Drains every wave's state stores to L2 (s_waitcnt vmcnt(0) before
        // s_barrier) and orders part[] reuse. All block stores happen-before
        // tid0's release-RMW below, whose buffer_wbl2 flushes them to L3.
        __syncthreads();
        if (tid == 0)
            __hip_atomic_fetch_add(&grpCnt[t + 1], 1, __ATOMIC_RELEASE,
                                   __HIP_MEMORY_SCOPE_AGENT);
    }
}

// ---------------------------------------------------------------------------
// Output GEMM: out[i][v] = sum_h states[i][h] * Wout[v][h] + bias[v]
// M=8192, N=8192, K=2048. BM=BN=128, BK=32, 256 thr = 2x2 waves of 64x64.
__launch_bounds__(256)
__global__ void out_gemm(const bf16_t* __restrict__ A,    // 8192 x 2048
                         const bf16_t* __restrict__ Bw,   // 8192 x 2048 [v][h]
                         const float* __restrict__ bias,  // 8192
                         float* __restrict__ out) {       // 8192 x 8192
    __shared__ uint4 AsU[2][128 * 5];
    __shared__ uint4 BsU[2][128 * 5];
    const int tid = threadIdx.x;
    const int wv = tid >> 6, lane = tid & 63;
    const int wm = wv >> 1, wn = wv & 1;
    const int q = lane >> 4, l15 = lane & 15;
    const int bm = blockIdx.y, bn = blockIdx.x;

    const uint4* gA = (const uint4*)A + (size_t)bm * 128 * 256;
    const uint4* gB = (const uint4*)Bw + (size_t)bn * 128 * 256;

    f32x4 acc[4][4];
#pragma unroll
    for (int mt = 0; mt < 4; mt++)
#pragma unroll
        for (int nt = 0; nt < 4; nt++)
            acc[mt][nt] = (f32x4){0.f, 0.f, 0.f, 0.f};

    uint4 pa[2], pb[2];
#pragma unroll
    for (int i = 0; i < 2; i++) {
        int v = tid + 256 * i;
        pa[i] = gA[(v >> 2) * 256 + (v & 3)];
        pb[i] = gB[(v >> 2) * 256 + (v & 3)];
    }
#pragma unroll
    for (int i = 0; i < 2; i++) {
        int v = tid + 256 * i;
        AsU[0][(v >> 2) * 5 + (v & 3)] = pa[i];
        BsU[0][(v >> 2) * 5 + (v & 3)] = pb[i];
    }
    __syncthreads();

    for (int it = 0; it < 64; ++it) {
        int cur = it & 1;
        if (it < 63) {
            int k0v = (it + 1) * 4;
#pragma unroll
            for (int i = 0; i < 2; i++) {
                int v = tid + 256 * i;
                pa[i] = gA[(v >> 2) * 256 + k0v + (v & 3)];
                pb[i] = gB[(v >> 2) * 256 + k0v + (v & 3)];
            }
        }
        bf16x8 af[4], bfr[4];
#pragma unroll
        for (int mt = 0; mt < 4; mt++)
            af[mt] = *(const bf16x8*)&AsU[cur][(wm * 64 + mt * 16 + l15) * 5 + q];
#pragma unroll
        for (int nt = 0; nt < 4; nt++)
            bfr[nt] = *(const bf16x8*)&BsU[cur][(wn * 64 + nt * 16 + l15) * 5 + q];
#pragma unroll
        for (int mt = 0; mt < 4; mt++)
#pragma unroll
            for (int nt = 0; nt < 4; nt++)
                acc[mt][nt] = __builtin_amdgcn_mfma_f32_16x16x32_bf16(
                    af[mt], bfr[nt], acc[mt][nt], 0, 0, 0);
        if (it < 63) {
            int nxt = cur ^ 1;
#pragma unroll
            for (int i = 0; i < 2; i++) {
                int v = tid + 256 * i;
                AsU[nxt][(v >> 2) * 5 + (v & 3)] = pa[i];
                BsU[nxt][(v >> 2) * 5 + (v & 3)] = pb[i];
            }
        }
        __syncthreads();
    }

#pragma unroll
    for (int nt = 0; nt < 4; nt++) {
        int col = bn * 128 + wn * 64 + nt * 16 + l15;
        float bv = bias[col];
#pragma unroll
        for (int mt = 0; mt < 4; mt++) {
#pragma unroll
            for (int i = 0; i < 4; i++) {
                int row = bm * 128 + wm * 64 + mt * 16 + q * 4 + i;
                out[(size_t)row * 8192 + col] = acc[mt][nt][i] + bv;
            }
        }
    }
}

// ---------------------------------------------------------------------------
extern "C" void kernel_launch(void* const* d_in, const int* in_sizes, int n_in,
                              void* d_out, int out_size, void* d_ws, size_t ws_size,
                              hipStream_t stream) {
    const int*   toks = (const int*)d_in[0];     // (T, B) token ids
    const float* hw   = (const float*)d_in[1];   // (H, V+H)
    const float* hb   = (const float*)d_in[2];   // (H,)
    const float* wo   = (const float*)d_in[3];   // (V, H)
    const float* ob   = (const float*)d_in[4];   // (V,)
    float* out = (float*)d_out;                  // T*B*V outputs then B*H final state

    // Workspace layout (bytes):
    //   states : (T+1)*B*H bf16 = 33,816,576   (slab 0 never touched by the
    //            recurrence -> its first 8 KB double as the barrier counters)
    //   whh    : H*H bf16       =  8,388,608
    //   woutb  : V*H bf16       = 33,554,432
    //   wembT  : V*H bf16       = 33,554,432   total ~109.3 MB
    char* ws = (char*)d_ws;
    bf16_t* states = (bf16_t*)ws;
    bf16_t* whh    = (bf16_t*)(ws + 33816576ULL);
    bf16_t* woutb  = (bf16_t*)(ws + 33816576ULL + 8388608ULL);
    bf16_t* wembT  = (bf16_t*)(ws + 33816576ULL + 8388608ULL + 33554432ULL);
    int*    cnt    = (int*)ws;                   // lives in unused state slab 0

    conv_whh<<<(HID * HID / 4) / 256, 256, 0, stream>>>(hw, whh, cnt);
    conv_wout<<<(VOCAB * HID / 4) / 256, 256, 0, stream>>>(wo, woutb);
    trans_emb<<<dim3(VOCAB / 32, HID / 32), dim3(32, 8), 0, stream>>>(hw, wembT);

    // Persistent cooperative recurrence: all 128 steps, Whh register-resident.
    float* fin = out + (size_t)T_STEPS * BATCH * VOCAB;
    void* args[] = { (void*)&states, (void*)&whh, (void*)&wembT,
                     (void*)&hb, (void*)&toks, (void*)&fin, (void*)&cnt };
    hipLaunchCooperativeKernel((void*)rnn_persist, dim3(256), dim3(512),
                               args, 0, stream);

    out_gemm<<<dim3(64, 64), 256, 0, stream>>>(
        states + (size_t)BH, woutb, ob, out);
}

// Round 2
// 1381.698 us; speedup vs baseline: 3.3493x; 2.6448x over previous
//
#include <hip/hip_runtime.h>

// Problem constants
#define T_STEPS 128
#define BATCH   64
#define VOCAB   8192
#define HID     2048
#define WROW    (VOCAB + HID)   // 10240, hidden_w row length
#define BH      (BATCH * HID)   // 131072, one state slab
#define CNT_STRIDE 512          // ints per bm-group counter array (padded)

typedef __bf16 bf16_t;
typedef __bf16 bf16x8 __attribute__((ext_vector_type(8)));
typedef float  f32x4  __attribute__((ext_vector_type(4)));
typedef unsigned long long u64;

// ---------------------------------------------------------------------------
// Convert W_hh = hidden_w[:, V:] (2048x2048 fp32) -> bf16, row-major [h][j].
// Block 0 additionally zeroes the step-barrier counters (stream-ordered
// before rnn_persist, so counters are reset on every kernel_launch call).
__global__ void conv_whh(const float* __restrict__ hw, bf16_t* __restrict__ whh,
                         int* __restrict__ cnt) {
    if (blockIdx.x == 0) {
        for (int i = threadIdx.x; i < 4 * CNT_STRIDE; i += 256) cnt[i] = 0;
    }
    int idx = blockIdx.x * 256 + threadIdx.x;
    int i4 = idx * 4;
    int h = i4 >> 11;
    int j = i4 & 2047;
    float4 w = *(const float4*)(hw + (size_t)h * WROW + VOCAB + j);
    union { bf16_t b[4]; uint2 u; } t;
    t.b[0] = (bf16_t)w.x; t.b[1] = (bf16_t)w.y; t.b[2] = (bf16_t)w.z; t.b[3] = (bf16_t)w.w;
    *(uint2*)(whh + (size_t)h * HID + j) = t.u;
}

// Convert output_w (8192x2048 fp32, contiguous) -> bf16
__global__ void conv_wout(const float* __restrict__ wo, bf16_t* __restrict__ wob) {
    size_t i4 = ((size_t)blockIdx.x * 256 + threadIdx.x) * 4;
    float4 w = *(const float4*)(wo + i4);
    union { bf16_t b[4]; uint2 u; } t;
    t.b[0] = (bf16_t)w.x; t.b[1] = (bf16_t)w.y; t.b[2] = (bf16_t)w.z; t.b[3] = (bf16_t)w.w;
    *(uint2*)(wob + i4) = t.u;
}

// Transpose+convert embedding block: wembT[v][h] = hidden_w[h][v], bf16
// grid (V/32, H/32), block (32, 8)
__global__ void trans_emb(const float* __restrict__ hw, bf16_t* __restrict__ wt) {
    __shared__ float tile[32][33];
    int tx = threadIdx.x, ty = threadIdx.y;
    int v0 = blockIdx.x * 32, h0 = blockIdx.y * 32;
#pragma unroll
    for (int i = 0; i < 4; i++)
        tile[ty + i * 8][tx] = hw[(size_t)(h0 + ty + i * 8) * WROW + v0 + tx];
    __syncthreads();
#pragma unroll
    for (int i = 0; i < 4; i++)
        wt[(size_t)(v0 + ty + i * 8) * HID + h0 + tx] = (bf16_t)tile[tx][ty + i * 8];
}

// ---------------------------------------------------------------------------
// Persistent cooperative recurrence kernel: all 128 steps in one launch.
// Grid 256 blocks x 512 threads. Block (bm,bn): bm = m-slice of 16 batch rows,
// bn = n-slice of 32 hidden cols. 8 waves split K (2048) -> 256 each.
// Whh slice lives in registers for the whole kernel (16 bf16x8 frags/lane).
//
// Sync redesign (round 2): per-op coherence instead of fences. All cross-block
// data (state slabs, step flags) moves via relaxed SYSTEM-scope atomics, which
// compile to bare global ops with sc0 sc1 (bypass L1/L2, read/write through to
// the LLC coherence point). This eliminates the per-step per-block
// buffer_wbl2 + buffer_inv that the release/acquire fences emitted — the mass
// L2 flush/invalidate ops that serialized ~20 us/step across 32 blocks/XCD.
// Ordering: __syncthreads() drains vmcnt (sc1 stores ack from LLC => visible),
// then one relaxed fetch_add publishes. Leader-lane-only poll cuts flag-line
// LLC contention 512x. Staleness is structurally impossible: each slab is
// written once / read once, and a block only re-reads bytes it wrote itself.
// Cooperative launch retained solely for the co-residency guarantee.
__launch_bounds__(512)
__global__ void rnn_persist(bf16_t* __restrict__ states,    // (T+1) slabs of 64x2048
                            const bf16_t* __restrict__ whh, // 2048 x 2048 [h][k]
                            const bf16_t* __restrict__ wembT,// 8192 x 2048 [v][h]
                            const float* __restrict__ hb,   // 2048
                            const int* __restrict__ toks,   // T*B
                            float* __restrict__ fin,        // 64 x 2048 fp32
                            int* __restrict__ cnt) {        // 4 * CNT_STRIDE ints
    __shared__ float part[8][512];                           // 16 KB

    const int tid = threadIdx.x;
    const int w = tid >> 6, lane = tid & 63;
    const int q = lane >> 4, l15 = lane & 15;
    const int bm = blockIdx.x & 3, bn = blockIdx.x >> 2;
    const int m0 = bm * 16, n0 = bn * 32;
    const int kb = w * 256;                                  // this wave's K base

    // Load persistent B fragments: B[n0+nt*16+l15][kb + kk*32 + q*8 .. +8]
    bf16x8 breg[2][8];
#pragma unroll
    for (int nt = 0; nt < 2; nt++)
#pragma unroll
        for (int kk = 0; kk < 8; kk++)
            breg[nt][kk] = *(const bf16x8*)(
                whh + (size_t)(n0 + nt * 16 + l15) * HID + kb + kk * 32 + q * 8);

    // Lane's A offset in u64 (4 x bf16) units
    const size_t abase8 = (size_t)((m0 + l15) * HID + kb + q * 8) >> 2;

    // Epilogue: 256 threads, 2 adjacent cols each (native 4-byte packed store)
    const int er = tid >> 4, ec = (tid & 15) * 2;            // er 0..31 (use <16)
    const int R = m0 + er, h = n0 + ec;
    float bias0 = 0.f, bias1 = 0.f;
    if (tid < 256) { bias0 = hb[h]; bias1 = hb[h + 1]; }
    int* grpCnt = cnt + bm * CNT_STRIDE;                     // this group's counters

    for (int t = 0; t < T_STEPS; ++t) {
        // State-independent prefetch (constants; normal cached loads are fine).
        float emb0 = 0.f, emb1 = 0.f;
        if (tid < 256) {
            int tok = toks[t * BATCH + R];
            emb0 = (float)wembT[(size_t)tok * HID + h];
            emb1 = (float)wembT[(size_t)tok * HID + h + 1];
        }

        f32x4 acc0 = (f32x4){0.f, 0.f, 0.f, 0.f};
        f32x4 acc1 = (f32x4){0.f, 0.f, 0.f, 0.f};
        if (t > 0) {
            // Leader-only poll: all 64 blocks of this bm-group published slab t.
            if (tid == 0) {
                while (__hip_atomic_load(&grpCnt[t], __ATOMIC_RELAXED,
                                         __HIP_MEMORY_SCOPE_SYSTEM) < 64)
                    __builtin_amdgcn_s_sleep(1);
            }
            __syncthreads();
            asm volatile("" ::: "memory");   // compiler barrier (no codegen)

            // A-tile: coherent sc0 sc1 loads straight from LLC (producers wrote
            // write-through, so no cache maintenance needed on either side).
            const u64* sprev = (const u64*)(states + (size_t)t * BH);
            u64 a8[16];
#pragma unroll
            for (int kk = 0; kk < 8; kk++) {
                a8[2 * kk]     = __hip_atomic_load(sprev + abase8 + kk * 8,
                                    __ATOMIC_RELAXED, __HIP_MEMORY_SCOPE_SYSTEM);
                a8[2 * kk + 1] = __hip_atomic_load(sprev + abase8 + kk * 8 + 1,
                                    __ATOMIC_RELAXED, __HIP_MEMORY_SCOPE_SYSTEM);
            }
#pragma unroll
            for (int kk = 0; kk < 8; kk++) {
                union { u64 u[2]; bf16x8 v; } cv;
                cv.u[0] = a8[2 * kk]; cv.u[1] = a8[2 * kk + 1];
                acc0 = __builtin_amdgcn_mfma_f32_16x16x32_bf16(cv.v, breg[0][kk], acc0, 0, 0, 0);
                acc1 = __builtin_amdgcn_mfma_f32_16x16x32_bf16(cv.v, breg[1][kk], acc1, 0, 0, 0);
            }
        }
        // write K-partials: C/D layout col = l15, row = q*4 + i
#pragma unroll
        for (int i = 0; i < 4; i++) {
            part[w][(q * 4 + i) * 32 + l15]      = acc0[i];
            part[w][(q * 4 + i) * 32 + 16 + l15] = acc1[i];
        }
        __syncthreads();
        // epilogue: 2 output elements per thread, packed 4-byte coherent store
        if (tid < 256) {
            float s0 = 0.f, s1 = 0.f;
#pragma unroll
            for (int ww = 0; ww < 8; ww++) {
                float2 p = *(const float2*)&part[ww][er * 32 + ec];
                s0 += p.x; s1 += p.y;
            }
            float v0 = tanhf(s0 + emb0 + bias0);
            float v1 = tanhf(s1 + emb1 + bias1);
            union { bf16_t b[2]; unsigned int u; } pk;
            pk.b[0] = (bf16_t)v0; pk.b[1] = (bf16_t)v1;
            __hip_atomic_store(
                (unsigned int*)(states + (size_t)(t + 1) * BH + R * HID + h),
                pk.u, __ATOMIC_RELAXED, __HIP_MEMORY_SCOPE_SYSTEM);
            if (t == T_STEPS - 1)
                *(float2*)&fin[R * HID + h] = make_float2(v0, v1);
        }
        // Barrier drains every wave's vmcnt: sc1 write-through stores are ack'd
        // from the LLC, so after this barrier the slab is globally visible.
        __syncthreads();
        asm volatile("" ::: "memory");       // compiler barrier (no codegen)
        if (tid == 0)
            __hip_atomic_fetch_add(&grpCnt[t + 1], 1, __ATOMIC_RELAXED,
                                   __HIP_MEMORY_SCOPE_SYSTEM);
    }
}

// ---------------------------------------------------------------------------
// Output GEMM: out[i][v] = sum_h states[i][h] * Wout[v][h] + bias[v]
// M=8192, N=8192, K=2048. BM=BN=128, BK=32, 256 thr = 2x2 waves of 64x64.
__launch_bounds__(256)
__global__ void out_gemm(const bf16_t* __restrict__ A,    // 8192 x 2048
                         const bf16_t* __restrict__ Bw,   // 8192 x 2048 [v][h]
                         const float* __restrict__ bias,  // 8192
                         float* __restrict__ out) {       // 8192 x 8192
    __shared__ uint4 AsU[2][128 * 5];
    __shared__ uint4 BsU[2][128 * 5];
    const int tid = threadIdx.x;
    const int wv = tid >> 6, lane = tid & 63;
    const int wm = wv >> 1, wn = wv & 1;
    const int q = lane >> 4, l15 = lane & 15;
    const int bm = blockIdx.y, bn = blockIdx.x;

    const uint4* gA = (const uint4*)A + (size_t)bm * 128 * 256;
    const uint4* gB = (const uint4*)Bw + (size_t)bn * 128 * 256;

    f32x4 acc[4][4];
#pragma unroll
    for (int mt = 0; mt < 4; mt++)
#pragma unroll
        for (int nt = 0; nt < 4; nt++)
            acc[mt][nt] = (f32x4){0.f, 0.f, 0.f, 0.f};

    uint4 pa[2], pb[2];
#pragma unroll
    for (int i = 0; i < 2; i++) {
        int v = tid + 256 * i;
        pa[i] = gA[(v >> 2) * 256 + (v & 3)];
        pb[i] = gB[(v >> 2) * 256 + (v & 3)];
    }
#pragma unroll
    for (int i = 0; i < 2; i++) {
        int v = tid + 256 * i;
        AsU[0][(v >> 2) * 5 + (v & 3)] = pa[i];
        BsU[0][(v >> 2) * 5 + (v & 3)] = pb[i];
    }
    __syncthreads();

    for (int it = 0; it < 64; ++it) {
        int cur = it & 1;
        if (it < 63) {
            int k0v = (it + 1) * 4;
#pragma unroll
            for (int i = 0; i < 2; i++) {
                int v = tid + 256 * i;
                pa[i] = gA[(v >> 2) * 256 + k0v + (v & 3)];
                pb[i] = gB[(v >> 2) * 256 + k0v + (v & 3)];
            }
        }
        bf16x8 af[4], bfr[4];
#pragma unroll
        for (int mt = 0; mt < 4; mt++)
            af[mt] = *(const bf16x8*)&AsU[cur][(wm * 64 + mt * 16 + l15) * 5 + q];
#pragma unroll
        for (int nt = 0; nt < 4; nt++)
            bfr[nt] = *(const bf16x8*)&BsU[cur][(wn * 64 + nt * 16 + l15) * 5 + q];
#pragma unroll
        for (int mt = 0; mt < 4; mt++)
#pragma unroll
            for (int nt = 0; nt < 4; nt++)
                acc[mt][nt] = __builtin_amdgcn_mfma_f32_16x16x32_bf16(
                    af[mt], bfr[nt], acc[mt][nt], 0, 0, 0);
        if (it < 63) {
            int nxt = cur ^ 1;
#pragma unroll
            for (int i = 0; i < 2; i++) {
                int v = tid + 256 * i;
                AsU[nxt][(v >> 2) * 5 + (v & 3)] = pa[i];
                BsU[nxt][(v >> 2) * 5 + (v & 3)] = pb[i];
            }
        }
        __syncthreads();
    }

#pragma unroll
    for (int nt = 0; nt < 4; nt++) {
        int col = bn * 128 + wn * 64 + nt * 16 + l15;
        float bv = bias[col];
#pragma unroll
        for (int mt = 0; mt < 4; mt++) {
#pragma unroll
            for (int i = 0; i < 4; i++) {
                int row = bm * 128 + wm * 64 + mt * 16 + q * 4 + i;
                out[(size_t)row * 8192 + col] = acc[mt][nt][i] + bv;
            }
        }
    }
}

// ---------------------------------------------------------------------------
extern "C" void kernel_launch(void* const* d_in, const int* in_sizes, int n_in,
                              void* d_out, int out_size, void* d_ws, size_t ws_size,
                              hipStream_t stream) {
    const int*   toks = (const int*)d_in[0];     // (T, B) token ids
    const float* hw   = (const float*)d_in[1];   // (H, V+H)
    const float* hb   = (const float*)d_in[2];   // (H,)
    const float* wo   = (const float*)d_in[3];   // (V, H)
    const float* ob   = (const float*)d_in[4];   // (V,)
    float* out = (float*)d_out;                  // T*B*V outputs then B*H final state

    // Workspace layout (bytes):
    //   states : (T+1)*B*H bf16 = 33,816,576   (slab 0 never touched by the
    //            recurrence -> its first 8 KB double as the barrier counters)
    //   whh    : H*H bf16       =  8,388,608
    //   woutb  : V*H bf16       = 33,554,432
    //   wembT  : V*H bf16       = 33,554,432   total ~109.3 MB
    char* ws = (char*)d_ws;
    bf16_t* states = (bf16_t*)ws;
    bf16_t* whh    = (bf16_t*)(ws + 33816576ULL);
    bf16_t* woutb  = (bf16_t*)(ws + 33816576ULL + 8388608ULL);
    bf16_t* wembT  = (bf16_t*)(ws + 33816576ULL + 8388608ULL + 33554432ULL);
    int*    cnt    = (int*)ws;                   // lives in unused state slab 0

    conv_whh<<<(HID * HID / 4) / 256, 256, 0, stream>>>(hw, whh, cnt);
    conv_wout<<<(VOCAB * HID / 4) / 256, 256, 0, stream>>>(wo, woutb);
    trans_emb<<<dim3(VOCAB / 32, HID / 32), dim3(32, 8), 0, stream>>>(hw, wembT);

    // Persistent cooperative recurrence: all 128 steps, Whh register-resident.
    float* fin = out + (size_t)T_STEPS * BATCH * VOCAB;
    void* args[] = { (void*)&states, (void*)&whh, (void*)&wembT,
                     (void*)&hb, (void*)&toks, (void*)&fin, (void*)&cnt };
    hipLaunchCooperativeKernel((void*)rnn_persist, dim3(256), dim3(512),
                               args, 0, stream);

    out_gemm<<<dim3(64, 64), 256, 0, stream>>>(
        states + (size_t)BH, woutb, ob, out);
}

// Round 3
// 1358.837 us; speedup vs baseline: 3.4057x; 1.0168x over previous
//
#include <hip/hip_runtime.h>

// Problem constants
#define T_STEPS 128
#define BATCH   64
#define VOCAB   8192
#define HID     2048
#define WROW    (VOCAB + HID)   // 10240, hidden_w row length
#define BH      (BATCH * HID)   // 131072, one state slab
#define CNT_STRIDE 512          // ints reserved per bm-group flag region

typedef __bf16 bf16_t;
typedef __bf16 bf16x8 __attribute__((ext_vector_type(8)));
typedef float  f32x4  __attribute__((ext_vector_type(4)));
typedef unsigned long long u64;
typedef const __attribute__((address_space(1))) unsigned int gu32;
typedef __attribute__((address_space(3))) unsigned int lu32;

// ---------------------------------------------------------------------------
// Convert W_hh = hidden_w[:, V:] (2048x2048 fp32) -> bf16, row-major [h][j].
// Block 0 additionally zeroes the step-barrier flags (stream-ordered before
// rnn_persist, so flags are reset on every kernel_launch call / graph replay).
__global__ void conv_whh(const float* __restrict__ hw, bf16_t* __restrict__ whh,
                         int* __restrict__ cnt) {
    if (blockIdx.x == 0) {
        for (int i = threadIdx.x; i < 4 * CNT_STRIDE; i += 256) cnt[i] = 0;
    }
    int idx = blockIdx.x * 256 + threadIdx.x;
    int i4 = idx * 4;
    int h = i4 >> 11;
    int j = i4 & 2047;
    float4 w = *(const float4*)(hw + (size_t)h * WROW + VOCAB + j);
    union { bf16_t b[4]; uint2 u; } t;
    t.b[0] = (bf16_t)w.x; t.b[1] = (bf16_t)w.y; t.b[2] = (bf16_t)w.z; t.b[3] = (bf16_t)w.w;
    *(uint2*)(whh + (size_t)h * HID + j) = t.u;
}

// Convert output_w (8192x2048 fp32, contiguous) -> bf16
__global__ void conv_wout(const float* __restrict__ wo, bf16_t* __restrict__ wob) {
    size_t i4 = ((size_t)blockIdx.x * 256 + threadIdx.x) * 4;
    float4 w = *(const float4*)(wo + i4);
    union { bf16_t b[4]; uint2 u; } t;
    t.b[0] = (bf16_t)w.x; t.b[1] = (bf16_t)w.y; t.b[2] = (bf16_t)w.z; t.b[3] = (bf16_t)w.w;
    *(uint2*)(wob + i4) = t.u;
}

// Transpose+convert embedding block: wembT[v][h] = hidden_w[h][v], bf16
// grid (V/32, H/32), block (32, 8)
__global__ void trans_emb(const float* __restrict__ hw, bf16_t* __restrict__ wt) {
    __shared__ float tile[32][33];
    int tx = threadIdx.x, ty = threadIdx.y;
    int v0 = blockIdx.x * 32, h0 = blockIdx.y * 32;
#pragma unroll
    for (int i = 0; i < 4; i++)
        tile[ty + i * 8][tx] = hw[(size_t)(h0 + ty + i * 8) * WROW + v0 + tx];
    __syncthreads();
#pragma unroll
    for (int i = 0; i < 4; i++)
        wt[(size_t)(v0 + ty + i * 8) * HID + h0 + tx] = (bf16_t)tile[tx][ty + i * 8];
}

// ---------------------------------------------------------------------------
// Persistent cooperative recurrence kernel: all 128 steps in one launch.
// Grid 256 blocks x 512 threads. Block (bm,bn): bm = m-slice of 16 batch rows,
// bn = n-slice of 32 hidden cols. 8 waves split K (2048) -> 256 each.
// Whh slice lives in registers for the whole kernel (16 bf16x8 frags/lane).
//
// Sync (round 3): per-op LLC coherence (relaxed system-scope atomics, sc0 sc1,
// no fences / cache maintenance) as in round 2, but the group barrier is now
// RMW-free: each block STOREs flag[bm][bn] = t+1 (64 parallel stores to 4
// lines, no same-address atomic serialization), and wave 0 of each consumer
// polls all 64 flags in parallel (one flag per lane, __all(v >= t)). This
// removes the ~2 us/step of serialized fetch_adds on one LLC line.
// Ordering: __syncthreads() drains vmcnt (sc1 write-through stores ack from
// LLC => globally visible), then the flag store publishes. Staleness is
// structurally impossible: each slab is written once / read once.
__launch_bounds__(512)
__global__ void rnn_persist(bf16_t* __restrict__ states,    // (T+1) slabs of 64x2048
                            const bf16_t* __restrict__ whh, // 2048 x 2048 [h][k]
                            const bf16_t* __restrict__ wembT,// 8192 x 2048 [v][h]
                            const float* __restrict__ hb,   // 2048
                            const int* __restrict__ toks,   // T*B
                            float* __restrict__ fin,        // 64 x 2048 fp32
                            int* __restrict__ cnt) {        // flags: cnt[bm*64+bn]
    __shared__ float part[8][512];                           // 16 KB

    const int tid = threadIdx.x;
    const int w = tid >> 6, lane = tid & 63;
    const int q = lane >> 4, l15 = lane & 15;
    const int bm = blockIdx.x & 3, bn = blockIdx.x >> 2;
    const int m0 = bm * 16, n0 = bn * 32;
    const int kb = w * 256;                                  // this wave's K base

    // Load persistent B fragments: B[n0+nt*16+l15][kb + kk*32 + q*8 .. +8]
    bf16x8 breg[2][8];
#pragma unroll
    for (int nt = 0; nt < 2; nt++)
#pragma unroll
        for (int kk = 0; kk < 8; kk++)
            breg[nt][kk] = *(const bf16x8*)(
                whh + (size_t)(n0 + nt * 16 + l15) * HID + kb + kk * 32 + q * 8);

    // Lane's A offset in u64 (4 x bf16) units
    const size_t abase8 = (size_t)((m0 + l15) * HID + kb + q * 8) >> 2;

    // Epilogue: 256 threads, 2 adjacent cols each (native 4-byte packed store)
    const int er = tid >> 4, ec = (tid & 15) * 2;
    const int R = m0 + er, h = n0 + ec;
    float bias0 = 0.f, bias1 = 0.f;
    if (tid < 256) { bias0 = hb[h]; bias1 = hb[h + 1]; }
    int* flags = cnt + bm * 64;                              // this group's 64 flags

    for (int t = 0; t < T_STEPS; ++t) {
        // State-independent prefetch (constants; normal cached loads are fine).
        float emb0 = 0.f, emb1 = 0.f;
        if (tid < 256) {
            int tok = toks[t * BATCH + R];
            union { unsigned int u; bf16_t b[2]; } e;
            e.u = *(const unsigned int*)(wembT + (size_t)tok * HID + h);
            emb0 = (float)e.b[0]; emb1 = (float)e.b[1];
        }

        f32x4 acc0 = (f32x4){0.f, 0.f, 0.f, 0.f};
        f32x4 acc1 = (f32x4){0.f, 0.f, 0.f, 0.f};
        if (t > 0) {
            // Parallel poll: lane j of wave 0 watches block (bm, j)'s flag.
            if (w == 0) {
                int v;
                do {
                    v = __hip_atomic_load(&flags[lane], __ATOMIC_RELAXED,
                                          __HIP_MEMORY_SCOPE_SYSTEM);
                } while (!__all(v >= t));
            }
            __syncthreads();
            asm volatile("" ::: "memory");   // compiler barrier (no codegen)

            // A-tile: coherent sc0 sc1 loads straight from LLC.
            const u64* sprev = (const u64*)(states + (size_t)t * BH);
            u64 a8[16];
#pragma unroll
            for (int kk = 0; kk < 8; kk++) {
                a8[2 * kk]     = __hip_atomic_load(sprev + abase8 + kk * 8,
                                    __ATOMIC_RELAXED, __HIP_MEMORY_SCOPE_SYSTEM);
                a8[2 * kk + 1] = __hip_atomic_load(sprev + abase8 + kk * 8 + 1,
                                    __ATOMIC_RELAXED, __HIP_MEMORY_SCOPE_SYSTEM);
            }
#pragma unroll
            for (int kk = 0; kk < 8; kk++) {
                union { u64 u[2]; bf16x8 v; } cv;
                cv.u[0] = a8[2 * kk]; cv.u[1] = a8[2 * kk + 1];
                acc0 = __builtin_amdgcn_mfma_f32_16x16x32_bf16(cv.v, breg[0][kk], acc0, 0, 0, 0);
                acc1 = __builtin_amdgcn_mfma_f32_16x16x32_bf16(cv.v, breg[1][kk], acc1, 0, 0, 0);
            }
        }
        // write K-partials: C/D layout col = l15, row = q*4 + i
#pragma unroll
        for (int i = 0; i < 4; i++) {
            part[w][(q * 4 + i) * 32 + l15]      = acc0[i];
            part[w][(q * 4 + i) * 32 + 16 + l15] = acc1[i];
        }
        __syncthreads();
        // epilogue: 2 output elements per thread, packed 4-byte coherent store
        if (tid < 256) {
            float s0 = 0.f, s1 = 0.f;
#pragma unroll
            for (int ww = 0; ww < 8; ww++) {
                float2 p = *(const float2*)&part[ww][er * 32 + ec];
                s0 += p.x; s1 += p.y;
            }
            float v0 = tanhf(s0 + emb0 + bias0);
            float v1 = tanhf(s1 + emb1 + bias1);
            union { bf16_t b[2]; unsigned int u; } pk;
            pk.b[0] = (bf16_t)v0; pk.b[1] = (bf16_t)v1;
            __hip_atomic_store(
                (unsigned int*)(states + (size_t)(t + 1) * BH + R * HID + h),
                pk.u, __ATOMIC_RELAXED, __HIP_MEMORY_SCOPE_SYSTEM);
            if (t == T_STEPS - 1)
                *(float2*)&fin[R * HID + h] = make_float2(v0, v1);
        }
        // Barrier drains every wave's vmcnt: sc1 write-through stores are ack'd
        // from the LLC, so after this barrier the slab is globally visible.
        __syncthreads();
        asm volatile("" ::: "memory");       // compiler barrier (no codegen)
        if (tid == 0)
            __hip_atomic_store(&flags[bn], t + 1, __ATOMIC_RELAXED,
                               __HIP_MEMORY_SCOPE_SYSTEM);
    }
}

// ---------------------------------------------------------------------------
// Output GEMM: out[i][v] = sum_h states[i][h] * Wout[v][h] + bias[v]
// M=8192, N=8192, K=2048. BM=BN=128, BK=32, 256 thr = 2x2 waves of 64x64.
// m97-style staging: global_load_lds width=16 into LINEAR [128][32] bf16
// tiles (lane-linear LDS landing = row*64B + kchunk*16B exactly), double
// buffered, one barrier per K-step.
__launch_bounds__(256)
__global__ void out_gemm(const bf16_t* __restrict__ A,    // 8192 x 2048
                         const bf16_t* __restrict__ Bw,   // 8192 x 2048 [v][h]
                         const float* __restrict__ bias,  // 8192
                         float* __restrict__ out) {       // 8192 x 8192
    __shared__ bf16_t As[2][128 * 32];   // 8 KB per buffer
    __shared__ bf16_t Bs[2][128 * 32];
    const int tid = threadIdx.x;
    const int wv = tid >> 6, lane = tid & 63;
    const int wm = wv >> 1, wn = wv & 1;
    const int q = lane >> 4, l15 = lane & 15;
    const int bm = blockIdx.y, bn = blockIdx.x;

    const bf16_t* gA = A  + (size_t)bm * 128 * 2048;
    const bf16_t* gB = Bw + (size_t)bn * 128 * 2048;

    // Staging: chunk c = i*4 + wv covers rows [c*16, c*16+16). Lane l lands at
    // LDS chunkbase + l*16 bytes == row (l>>2), kbytes (l&3)*16 of the chunk.
    const int sRow = lane >> 2;          // 0..15 within chunk
    const int sCol = (lane & 3) * 8;     // elem offset within BK=32

#define STAGE_TILE(dstBuf, gsrc, k0)                                          \
    do {                                                                      \
        _Pragma("unroll")                                                     \
        for (int i_ = 0; i_ < 2; i_++) {                                      \
            int chunk_ = i_ * 4 + wv;                                         \
            __builtin_amdgcn_global_load_lds(                                 \
                (gu32*)(gsrc + ((size_t)(chunk_ * 16 + sRow)) * 2048 + (k0) + sCol), \
                (lu32*)(dstBuf + chunk_ * 16 * 32), 16, 0, 0);                \
        }                                                                     \
    } while (0)

    f32x4 acc[4][4];
#pragma unroll
    for (int mt = 0; mt < 4; mt++)
#pragma unroll
        for (int nt = 0; nt < 4; nt++)
            acc[mt][nt] = (f32x4){0.f, 0.f, 0.f, 0.f};

    // prologue: stage K-step 0 into buffer 0
    STAGE_TILE(As[0], gA, 0);
    STAGE_TILE(Bs[0], gB, 0);
    __syncthreads();

    for (int it = 0; it < 64; ++it) {
        int cur = it & 1;
        if (it < 63) {
            int k0 = (it + 1) * 32;
            STAGE_TILE(As[cur ^ 1], gA, k0);
            STAGE_TILE(Bs[cur ^ 1], gB, k0);
        }
        bf16x8 af[4], bfr[4];
#pragma unroll
        for (int mt = 0; mt < 4; mt++)
            af[mt] = *(const bf16x8*)&As[cur][(wm * 64 + mt * 16 + l15) * 32 + q * 8];
#pragma unroll
        for (int nt = 0; nt < 4; nt++)
            bfr[nt] = *(const bf16x8*)&Bs[cur][(wn * 64 + nt * 16 + l15) * 32 + q * 8];
#pragma unroll
        for (int mt = 0; mt < 4; mt++)
#pragma unroll
            for (int nt = 0; nt < 4; nt++)
                acc[mt][nt] = __builtin_amdgcn_mfma_f32_16x16x32_bf16(
                    af[mt], bfr[nt], acc[mt][nt], 0, 0, 0);
        // Barrier: drains lgkm (ds_reads of cur done -> next iter may overwrite)
        // and vmcnt (staged cur^1 landed -> next iter may read it).
        __syncthreads();
    }
#undef STAGE_TILE

#pragma unroll
    for (int nt = 0; nt < 4; nt++) {
        int col = bn * 128 + wn * 64 + nt * 16 + l15;
        float bv = bias[col];
#pragma unroll
        for (int mt = 0; mt < 4; mt++) {
#pragma unroll
            for (int i = 0; i < 4; i++) {
                int row = bm * 128 + wm * 64 + mt * 16 + q * 4 + i;
                out[(size_t)row * 8192 + col] = acc[mt][nt][i] + bv;
            }
        }
    }
}

// ---------------------------------------------------------------------------
extern "C" void kernel_launch(void* const* d_in, const int* in_sizes, int n_in,
                              void* d_out, int out_size, void* d_ws, size_t ws_size,
                              hipStream_t stream) {
    const int*   toks = (const int*)d_in[0];     // (T, B) token ids
    const float* hw   = (const float*)d_in[1];   // (H, V+H)
    const float* hb   = (const float*)d_in[2];   // (H,)
    const float* wo   = (const float*)d_in[3];   // (V, H)
    const float* ob   = (const float*)d_in[4];   // (V,)
    float* out = (float*)d_out;                  // T*B*V outputs then B*H final state

    // Workspace layout (bytes):
    //   states : (T+1)*B*H bf16 = 33,816,576   (slab 0 never touched by the
    //            recurrence -> its first 8 KB double as the barrier flags)
    //   whh    : H*H bf16       =  8,388,608
    //   woutb  : V*H bf16       = 33,554,432
    //   wembT  : V*H bf16       = 33,554,432   total ~109.3 MB
    char* ws = (char*)d_ws;
    bf16_t* states = (bf16_t*)ws;
    bf16_t* whh    = (bf16_t*)(ws + 33816576ULL);
    bf16_t* woutb  = (bf16_t*)(ws + 33816576ULL + 8388608ULL);
    bf16_t* wembT  = (bf16_t*)(ws + 33816576ULL + 8388608ULL + 33554432ULL);
    int*    cnt    = (int*)ws;                   // lives in unused state slab 0

    conv_whh<<<(HID * HID / 4) / 256, 256, 0, stream>>>(hw, whh, cnt);
    conv_wout<<<(VOCAB * HID / 4) / 256, 256, 0, stream>>>(wo, woutb);
    trans_emb<<<dim3(VOCAB / 32, HID / 32), dim3(32, 8), 0, stream>>>(hw, wembT);

    // Persistent cooperative recurrence: all 128 steps, Whh register-resident.
    float* fin = out + (size_t)T_STEPS * BATCH * VOCAB;
    void* args[] = { (void*)&states, (void*)&whh, (void*)&wembT,
                     (void*)&hb, (void*)&toks, (void*)&fin, (void*)&cnt };
    hipLaunchCooperativeKernel((void*)rnn_persist, dim3(256), dim3(512),
                               args, 0, stream);

    out_gemm<<<dim3(64, 64), 256, 0, stream>>>(
        states + (size_t)BH, woutb, ob, out);
}